// Round 1
// baseline (1059.706 us; speedup 1.0000x reference)
//
#include <hip/hip_runtime.h>
#include <hip/hip_bf16.h>
#include <math.h>

// Problem constants: B=4, L=96, D=256, H=8, hd=32, FF=1024
// M = B*L*L = 36864 rows of D=256.
#define M_ROWS 36864

// ---------------- pack Wq|Wk|Wv -> [256,768], bq|bk|bv -> [768] ----------------
__global__ void pack_qkv_kernel(const float* __restrict__ Wq, const float* __restrict__ Wk,
                                const float* __restrict__ Wv, const float* __restrict__ bq,
                                const float* __restrict__ bk, const float* __restrict__ bv,
                                float* __restrict__ Wqkv, float* __restrict__ bqkv) {
  int idx = blockIdx.x * 256 + threadIdx.x;
  if (idx < 256 * 768) {
    int k = idx / 768, j = idx % 768;
    int sel = j >> 8, jj = j & 255;
    const float* W = (sel == 0) ? Wq : (sel == 1) ? Wk : Wv;
    Wqkv[idx] = W[k * 256 + jj];
  }
  if (idx < 768) {
    int sel = idx >> 8, jj = idx & 255;
    const float* bsrc = (sel == 0) ? bq : (sel == 1) ? bk : bv;
    bqkv[idx] = bsrc[jj];
  }
}

// ---------------- fp32 tiled GEMM: C[M,N] = A[M,K] @ B[K,N] + bias (+epi) ------
// EPI: 0 = bias, 1 = bias+relu, 2 = bias+residual
// 64x64 tile, 256 threads, 4x4 microtile. M,N divisible by 64; K by 16.
template <int EPI>
__global__ __launch_bounds__(256) void gemm_kernel(
    const float* __restrict__ A, const float* __restrict__ B,
    const float* __restrict__ bias, const float* __restrict__ resid,
    float* __restrict__ C, int N, int K) {
  __shared__ float As[16][64];  // [k][m] (transposed on store)
  __shared__ float Bs[16][64];  // [k][n]
  const int tid = threadIdx.x;
  const int n0 = blockIdx.x * 64;
  const int m0 = blockIdx.y * 64;
  const int tx = tid & 15, ty = tid >> 4;
  const int arow = tid >> 2, akk = (tid & 3) << 2;
  const int brow = tid >> 4, bcol = (tid & 15) << 2;
  float acc[4][4] = {};
  const float* Aptr = A + (size_t)(m0 + arow) * K + akk;
  const float* Bptr = B + (size_t)brow * N + n0 + bcol;
  for (int kb = 0; kb < K; kb += 16) {
    float4 a4 = *(const float4*)(Aptr + kb);
    float4 b4 = *(const float4*)(Bptr + (size_t)kb * N);
    __syncthreads();  // protect previous iteration's LDS reads
    As[akk + 0][arow] = a4.x;
    As[akk + 1][arow] = a4.y;
    As[akk + 2][arow] = a4.z;
    As[akk + 3][arow] = a4.w;
    *(float4*)&Bs[brow][bcol] = b4;
    __syncthreads();
#pragma unroll
    for (int k = 0; k < 16; ++k) {
      float4 a = *(const float4*)&As[k][ty << 2];
      float4 b = *(const float4*)&Bs[k][tx << 2];
      float av[4] = {a.x, a.y, a.z, a.w};
      float bv[4] = {b.x, b.y, b.z, b.w};
#pragma unroll
      for (int i = 0; i < 4; ++i)
#pragma unroll
        for (int j = 0; j < 4; ++j) acc[i][j] += av[i] * bv[j];
    }
  }
  const int col = n0 + (tx << 2);
  const float4 bias4 = *(const float4*)&bias[col];
  const float bb[4] = {bias4.x, bias4.y, bias4.z, bias4.w};
#pragma unroll
  for (int i = 0; i < 4; ++i) {
    const int row = m0 + (ty << 2) + i;
    float rr[4] = {0.f, 0.f, 0.f, 0.f};
    if (EPI == 2) {
      float4 r4 = *(const float4*)&resid[(size_t)row * N + col];
      rr[0] = r4.x; rr[1] = r4.y; rr[2] = r4.z; rr[3] = r4.w;
    }
    float4 o;
    float* op = &o.x;
#pragma unroll
    for (int j = 0; j < 4; ++j) {
      float v = acc[i][j] + bb[j];
      if (EPI == 1) v = fmaxf(v, 0.f);
      if (EPI == 2) v += rr[j];
      op[j] = v;
    }
    *(float4*)&C[(size_t)row * N + col] = o;
  }
}

// ---------------- attention: one block per (b,h,x) ----------------
// q,k,v slices [96,32] staged in LDS; 4 waves, each wave owns rows r = wave+4t.
__global__ __launch_bounds__(256) void attn_kernel(
    const float* __restrict__ qkv, const float* __restrict__ depm,
    const float* __restrict__ Wdep, const float* __restrict__ bdep,
    float* __restrict__ ctx) {
  __shared__ float qs[96][32];
  __shared__ float ks[96][33];  // +1 pad: kills stride-32 bank conflict
  __shared__ float vs[96][33];
  __shared__ float depb[96];
  __shared__ float prow[4][96];
  const int bid = blockIdx.x;
  const int x = bid % 96;
  const int h = (bid / 96) % 8;
  const int b = bid / (96 * 8);
  const int tid = threadIdx.x;
  const size_t slab = (size_t)(b * 96 + x) * 96;   // row base in [36864]
  const size_t base = slab * 768 + h * 32;         // into qkv [M,768]
  for (int slot = tid; slot < 96 * 8; slot += 256) {
    const int r = slot >> 3, d = (slot & 7) << 2;
    const size_t ro = base + (size_t)r * 768 + d;
    float4 q4 = *(const float4*)&qkv[ro];
    float4 k4 = *(const float4*)&qkv[ro + 256];
    float4 v4 = *(const float4*)&qkv[ro + 512];
    *(float4*)&qs[r][d] = q4;
    ks[r][d] = k4.x; ks[r][d + 1] = k4.y; ks[r][d + 2] = k4.z; ks[r][d + 3] = k4.w;
    vs[r][d] = v4.x; vs[r][d + 1] = v4.y; vs[r][d + 2] = v4.z; vs[r][d + 3] = v4.w;
  }
  const float wd = Wdep[h], bd = bdep[h];
  for (int c = tid; c < 96; c += 256) depb[c] = depm[slab + c] * wd + bd;
  __syncthreads();
  const int wave = tid >> 6, lane = tid & 63;
  const int c1 = 64 + (lane & 31);
  const bool has1 = lane < 32;
  const int dd = lane & 31, half = lane >> 5;
  const float scale = 0.17677669529663687f;  // 1/sqrt(32)
  for (int it = 0; it < 24; ++it) {
    const int r = wave + it * 4;
    float qreg[32];
#pragma unroll
    for (int d = 0; d < 32; ++d) qreg[d] = qs[r][d];
    float s0 = 0.f, s1 = 0.f;
#pragma unroll
    for (int d = 0; d < 32; ++d) {
      s0 += qreg[d] * ks[lane][d];
      s1 += qreg[d] * ks[c1][d];
    }
    s0 = s0 * scale + depb[lane];
    s1 = s1 * scale + depb[c1];
    float m = fmaxf(s0, has1 ? s1 : -1e30f);
#pragma unroll
    for (int o = 32; o > 0; o >>= 1) m = fmaxf(m, __shfl_xor(m, o));
    const float e0 = __expf(s0 - m);
    const float e1 = has1 ? __expf(s1 - m) : 0.f;
    float sum = e0 + e1;
#pragma unroll
    for (int o = 32; o > 0; o >>= 1) sum += __shfl_xor(sum, o);
    const float inv = 1.0f / sum;
    prow[wave][lane] = e0 * inv;
    if (has1) prow[wave][64 + lane] = e1 * inv;
    __syncthreads();
    float acc = 0.f;
#pragma unroll
    for (int c = 0; c < 48; ++c)
      acc += prow[wave][half * 48 + c] * vs[half * 48 + c][dd];
    acc += __shfl_xor(acc, 32);
    if (has1) ctx[(slab + r) * 256 + h * 32 + dd] = acc;
    __syncthreads();
  }
}

// ---------------- LayerNorm over last dim 256; wave per row ----------------
__global__ __launch_bounds__(256) void ln_kernel(const float* __restrict__ X,
                                                 const float* __restrict__ g,
                                                 const float* __restrict__ beta,
                                                 float* __restrict__ Y) {
  const int row = blockIdx.x * 4 + (threadIdx.x >> 6);
  const int lane = threadIdx.x & 63;
  const size_t base = (size_t)row * 256 + lane * 4;
  float4 x4 = *(const float4*)&X[base];
  float xs[4] = {x4.x, x4.y, x4.z, x4.w};
  float s = xs[0] + xs[1] + xs[2] + xs[3];
#pragma unroll
  for (int o = 32; o > 0; o >>= 1) s += __shfl_xor(s, o);
  const float mean = s * (1.0f / 256.0f);
  float vsum = 0.f;
#pragma unroll
  for (int j = 0; j < 4; ++j) { float d = xs[j] - mean; vsum += d * d; }
#pragma unroll
  for (int o = 32; o > 0; o >>= 1) vsum += __shfl_xor(vsum, o);
  const float inv = rsqrtf(vsum * (1.0f / 256.0f) + 1e-5f);
  float4 g4 = *(const float4*)&g[lane * 4];
  float4 b4 = *(const float4*)&beta[lane * 4];
  float gg[4] = {g4.x, g4.y, g4.z, g4.w};
  float bb[4] = {b4.x, b4.y, b4.z, b4.w};
  float4 y4;
  float* yp = &y4.x;
#pragma unroll
  for (int j = 0; j < 4; ++j) yp[j] = (xs[j] - mean) * inv * gg[j] + bb[j];
  *(float4*)&Y[base] = y4;
}

extern "C" void kernel_launch(void* const* d_in, const int* in_sizes, int n_in,
                              void* d_out, int out_size, void* d_ws, size_t ws_size,
                              hipStream_t stream) {
  (void)in_sizes; (void)n_in; (void)out_size; (void)ws_size;
  const float* table = (const float*)d_in[0];
  const float* depm  = (const float*)d_in[1];
  const float* Wq = (const float*)d_in[2];   const float* bq = (const float*)d_in[3];
  const float* Wk = (const float*)d_in[4];   const float* bk = (const float*)d_in[5];
  const float* Wv = (const float*)d_in[6];   const float* bv = (const float*)d_in[7];
  const float* Wo = (const float*)d_in[8];   const float* bo = (const float*)d_in[9];
  const float* Wdep = (const float*)d_in[10]; const float* bdep = (const float*)d_in[11];
  const float* g1 = (const float*)d_in[12];  const float* be1 = (const float*)d_in[13];
  const float* W1 = (const float*)d_in[14];  const float* b1 = (const float*)d_in[15];
  const float* W2 = (const float*)d_in[16];  const float* b2 = (const float*)d_in[17];
  const float* g2 = (const float*)d_in[18];  const float* be2 = (const float*)d_in[19];

  // ws layout (bytes):
  //   bufA  : 36864*1024*4 = 150994944  (qkv [M,768] then hidden [M,1024])
  //   ctx   : 36864*256*4  =  37748736
  //   tmp   : 36864*256*4  =  37748736  (pre-LN1, then pre-LN2)
  //   outb  : 36864*256*4  =  37748736  (post-LN1)
  //   Wqkv  : 256*768*4    =    786432 ; bqkv: 768*4
  char* ws = (char*)d_ws;
  float* bufA = (float*)(ws);
  float* ctx  = (float*)(ws + 150994944);
  float* tmp  = (float*)(ws + 150994944 + 37748736);
  float* outb = (float*)(ws + 150994944 + 2 * 37748736);
  float* Wqkv = (float*)(ws + 150994944 + (size_t)3 * 37748736);
  float* bqkv = Wqkv + 256 * 768;

  pack_qkv_kernel<<<768, 256, 0, stream>>>(Wq, Wk, Wv, bq, bk, bv, Wqkv, bqkv);
  // qkv = table @ Wqkv + bqkv          [36864, 768]
  gemm_kernel<0><<<dim3(12, 576), 256, 0, stream>>>(table, Wqkv, bqkv, nullptr, bufA, 768, 256);
  // attention -> ctx                   [36864, 256]
  attn_kernel<<<3072, 256, 0, stream>>>(bufA, depm, Wdep, bdep, ctx);
  // tmp = ctx @ Wo + bo + table        [36864, 256]
  gemm_kernel<2><<<dim3(4, 576), 256, 0, stream>>>(ctx, Wo, bo, table, tmp, 256, 256);
  // outb = LN1(tmp)
  ln_kernel<<<9216, 256, 0, stream>>>(tmp, g1, be1, outb);
  // hidden = relu(outb @ W1 + b1)      [36864, 1024]
  gemm_kernel<1><<<dim3(16, 576), 256, 0, stream>>>(outb, W1, b1, nullptr, bufA, 1024, 256);
  // tmp = hidden @ W2 + b2 + outb      [36864, 256]
  gemm_kernel<2><<<dim3(4, 576), 256, 0, stream>>>(bufA, W2, b2, outb, tmp, 256, 1024);
  // d_out = LN2(tmp)
  ln_kernel<<<9216, 256, 0, stream>>>(tmp, g2, be2, (float*)d_out);
}

// Round 2
// 433.721 us; speedup vs baseline: 2.4433x; 2.4433x over previous
//
#include <hip/hip_runtime.h>
#include <hip/hip_bf16.h>
#include <math.h>

// Problem constants: B=4, L=96, D=256, H=8, hd=32, FF=1024. M = B*L*L = 36864.
#define M_ROWS 36864

typedef __bf16 bf16x8 __attribute__((ext_vector_type(8)));
typedef float f32x4 __attribute__((ext_vector_type(4)));

__device__ __forceinline__ void gload16(const void* g, void* l) {
  __builtin_amdgcn_global_load_lds((const __attribute__((address_space(1))) void*)g,
                                   (__attribute__((address_space(3))) void*)l, 16, 0, 0);
}

// ---------------- convert table fp32 -> bf16 ----------------
__global__ __launch_bounds__(256) void cvt_bf16_kernel(const float* __restrict__ X,
                                                       __bf16* __restrict__ Y, int n4) {
  int i = blockIdx.x * 256 + threadIdx.x;
  if (i >= n4) return;
  float4 x = *(const float4*)&X[(size_t)i * 4];
  __bf16* y = Y + (size_t)i * 4;
  y[0] = (__bf16)x.x; y[1] = (__bf16)x.y; y[2] = (__bf16)x.z; y[3] = (__bf16)x.w;
}

// ---------------- pack + transpose weights to bf16 B^T [N,K] ----------------
// Wqkv_t[768][256], Wo_t[256][256], W1_t[1024][256], W2_t[256][1024], bqkv[768]
__global__ __launch_bounds__(256) void pack_w_kernel(
    const float* __restrict__ Wq, const float* __restrict__ Wk, const float* __restrict__ Wv,
    const float* __restrict__ Wo, const float* __restrict__ W1, const float* __restrict__ W2,
    const float* __restrict__ bq, const float* __restrict__ bk, const float* __restrict__ bv,
    __bf16* __restrict__ Wqkv_t, __bf16* __restrict__ Wo_t,
    __bf16* __restrict__ W1_t, __bf16* __restrict__ W2_t, float* __restrict__ bqkv) {
  int idx = blockIdx.x * 256 + threadIdx.x;
  const int S1 = 768 * 256, S2 = 256 * 256, S3 = 1024 * 256;
  if (idx < S1) {
    int n = idx / 256, k = idx % 256;
    int sel = n >> 8, nn = n & 255;
    const float* W = (sel == 0) ? Wq : (sel == 1) ? Wk : Wv;
    Wqkv_t[idx] = (__bf16)W[k * 256 + nn];
  } else if (idx < S1 + S2) {
    int j = idx - S1; int n = j / 256, k = j % 256;
    Wo_t[j] = (__bf16)Wo[k * 256 + n];
  } else if (idx < S1 + S2 + S3) {
    int j = idx - S1 - S2; int n = j / 256, k = j % 256;
    W1_t[j] = (__bf16)W1[k * 1024 + n];
  } else {
    int j = idx - S1 - S2 - S3; int n = j / 1024, k = j % 1024;
    W2_t[j] = (__bf16)W2[k * 256 + n];
  }
  if (idx < 768) {
    int sel = idx >> 8, jj = idx & 255;
    const float* bsrc = (sel == 0) ? bq : (sel == 1) ? bk : bv;
    bqkv[idx] = bsrc[jj];
  }
}

// ---------------- bf16 MFMA GEMM (m97 structure) ----------------
// C[M,N] = A[M,K] @ Bt[N,K]^T + bias, epilogue variants.
// 128x128 tile, 4 waves, each wave 64x64 via 4x4 frags of 16x16x32.
// EPI: 0 = bias, 1 = bias+relu, 2 = bias+fp32 residual. OBF: bf16 output.
template <int EPI, bool OBF>
__global__ __launch_bounds__(256) void gemm_mfma_kernel(
    const __bf16* __restrict__ A, const __bf16* __restrict__ Bt,
    const float* __restrict__ bias, const float* __restrict__ resid,
    void* __restrict__ Cout, int N, int K) {
  __shared__ __bf16 As[128 * 64];
  __shared__ __bf16 Bs[128 * 64];
  const int tid = threadIdx.x;
  const int lane = tid & 63, wv = tid >> 6;
  const int wm = wv >> 1, wn = wv & 1;
  const int n0 = blockIdx.x * 128;
  const int m0 = blockIdx.y * 128;
  const int lrow = lane >> 3;         // 0..7
  const int lcol = (lane & 7) * 8;    // staging col (elements)
  const int fr = lane & 15;           // fragment row
  const int fk = (lane >> 4) * 8;     // fragment k offset

  f32x4 acc[4][4] = {};

  for (int kb = 0; kb < K; kb += 64) {
    __syncthreads();   // previous tile's LDS reads complete
#pragma unroll
    for (int i = 0; i < 4; ++i) {
      const int row = i * 32 + wv * 8 + lrow;
      gload16(A + (size_t)(m0 + row) * K + kb + lcol, &As[i * 2048 + wv * 512]);
      gload16(Bt + (size_t)(n0 + row) * K + kb + lcol, &Bs[i * 2048 + wv * 512]);
    }
    __syncthreads();   // drains vmcnt: staged data visible
#pragma unroll
    for (int s = 0; s < 2; ++s) {
      bf16x8 av[4], bv[4];
#pragma unroll
      for (int mi = 0; mi < 4; ++mi)
        av[mi] = *reinterpret_cast<const bf16x8*>(&As[(wm * 64 + mi * 16 + fr) * 64 + s * 32 + fk]);
#pragma unroll
      for (int ni = 0; ni < 4; ++ni)
        bv[ni] = *reinterpret_cast<const bf16x8*>(&Bs[(wn * 64 + ni * 16 + fr) * 64 + s * 32 + fk]);
#pragma unroll
      for (int mi = 0; mi < 4; ++mi)
#pragma unroll
        for (int ni = 0; ni < 4; ++ni)
          acc[mi][ni] = __builtin_amdgcn_mfma_f32_16x16x32_bf16(av[mi], bv[ni], acc[mi][ni], 0, 0, 0);
    }
  }

  // epilogue: C/D layout col=lane&15, row=(lane>>4)*4+reg
  const int crow = m0 + wm * 64 + (lane >> 4) * 4;
  const int ccol = n0 + wn * 64 + (lane & 15);
  __hip_bfloat16* outb = (__hip_bfloat16*)Cout;
  float* outf = (float*)Cout;
#pragma unroll
  for (int mi = 0; mi < 4; ++mi) {
#pragma unroll
    for (int ni = 0; ni < 4; ++ni) {
      const int col = ccol + ni * 16;
      const float bb = bias[col];
#pragma unroll
      for (int r = 0; r < 4; ++r) {
        const int row = crow + mi * 16 + r;
        float v = acc[mi][ni][r] + bb;
        if (EPI == 1) v = fmaxf(v, 0.f);
        if (EPI == 2) v += resid[(size_t)row * N + col];
        if (OBF) outb[(size_t)row * N + col] = __float2bfloat16(v);
        else     outf[(size_t)row * N + col] = v;
      }
    }
  }
}

// ---------------- attention: one block per (b,h,x); bf16 in, bf16 out --------
__global__ __launch_bounds__(256) void attn_kernel(
    const __bf16* __restrict__ qkv, const float* __restrict__ depm,
    const float* __restrict__ Wdep, const float* __restrict__ bdep,
    __hip_bfloat16* __restrict__ ctx) {
  __shared__ float qs[96][32];
  __shared__ float ks[96][33];  // +1 pad: kills stride-32 bank conflict
  __shared__ float vs[96][33];
  __shared__ float depb[96];
  __shared__ float prow[4][96];
  const int bid = blockIdx.x;
  const int x = bid % 96;
  const int h = (bid / 96) % 8;
  const int b = bid / (96 * 8);
  const int tid = threadIdx.x;
  const size_t slab = (size_t)(b * 96 + x) * 96;   // row base in [36864]
  const size_t base = slab * 768 + h * 32;         // into qkv [M,768]
  for (int slot = tid; slot < 96 * 4; slot += 256) {
    const int r = slot >> 2, d0 = (slot & 3) << 3;
    const size_t ro = base + (size_t)r * 768 + d0;
    bf16x8 q8 = *(const bf16x8*)&qkv[ro];
    bf16x8 k8 = *(const bf16x8*)&qkv[ro + 256];
    bf16x8 v8 = *(const bf16x8*)&qkv[ro + 512];
#pragma unroll
    for (int e = 0; e < 8; ++e) {
      qs[r][d0 + e] = (float)q8[e];
      ks[r][d0 + e] = (float)k8[e];
      vs[r][d0 + e] = (float)v8[e];
    }
  }
  const float wd = Wdep[h], bd = bdep[h];
  for (int c = tid; c < 96; c += 256) depb[c] = depm[slab + c] * wd + bd;
  __syncthreads();
  const int wave = tid >> 6, lane = tid & 63;
  const int c1 = 64 + (lane & 31);
  const bool has1 = lane < 32;
  const int dd = lane & 31, half = lane >> 5;
  const float scale = 0.17677669529663687f;  // 1/sqrt(32)
  for (int it = 0; it < 24; ++it) {
    const int r = wave + it * 4;
    float qreg[32];
#pragma unroll
    for (int d = 0; d < 32; ++d) qreg[d] = qs[r][d];
    float s0 = 0.f, s1 = 0.f;
#pragma unroll
    for (int d = 0; d < 32; ++d) {
      s0 += qreg[d] * ks[lane][d];
      s1 += qreg[d] * ks[c1][d];
    }
    s0 = s0 * scale + depb[lane];
    s1 = s1 * scale + depb[c1];
    float m = fmaxf(s0, has1 ? s1 : -1e30f);
#pragma unroll
    for (int o = 32; o > 0; o >>= 1) m = fmaxf(m, __shfl_xor(m, o));
    const float e0 = __expf(s0 - m);
    const float e1 = has1 ? __expf(s1 - m) : 0.f;
    float sum = e0 + e1;
#pragma unroll
    for (int o = 32; o > 0; o >>= 1) sum += __shfl_xor(sum, o);
    const float inv = 1.0f / sum;
    prow[wave][lane] = e0 * inv;
    if (has1) prow[wave][64 + lane] = e1 * inv;
    __syncthreads();
    float acc = 0.f;
#pragma unroll
    for (int c = 0; c < 48; ++c)
      acc += prow[wave][half * 48 + c] * vs[half * 48 + c][dd];
    acc += __shfl_xor(acc, 32);
    if (has1) ctx[(slab + r) * 256 + h * 32 + dd] = __float2bfloat16(acc);
    __syncthreads();
  }
}

// ---------------- LayerNorm over last dim 256; wave per row ----------------
template <bool BF16OUT>
__global__ __launch_bounds__(256) void ln_kernel(const float* __restrict__ X,
                                                 const float* __restrict__ g,
                                                 const float* __restrict__ beta,
                                                 float* __restrict__ Y,
                                                 __hip_bfloat16* __restrict__ Y2) {
  const int row = blockIdx.x * 4 + (threadIdx.x >> 6);
  const int lane = threadIdx.x & 63;
  const size_t base = (size_t)row * 256 + lane * 4;
  float4 x4 = *(const float4*)&X[base];
  float xs[4] = {x4.x, x4.y, x4.z, x4.w};
  float s = xs[0] + xs[1] + xs[2] + xs[3];
#pragma unroll
  for (int o = 32; o > 0; o >>= 1) s += __shfl_xor(s, o);
  const float mean = s * (1.0f / 256.0f);
  float vsum = 0.f;
#pragma unroll
  for (int j = 0; j < 4; ++j) { float d = xs[j] - mean; vsum += d * d; }
#pragma unroll
  for (int o = 32; o > 0; o >>= 1) vsum += __shfl_xor(vsum, o);
  const float inv = rsqrtf(vsum * (1.0f / 256.0f) + 1e-5f);
  float4 g4 = *(const float4*)&g[lane * 4];
  float4 b4 = *(const float4*)&beta[lane * 4];
  float gg[4] = {g4.x, g4.y, g4.z, g4.w};
  float bb[4] = {b4.x, b4.y, b4.z, b4.w};
  float4 y4;
  float* yp = &y4.x;
#pragma unroll
  for (int j = 0; j < 4; ++j) yp[j] = (xs[j] - mean) * inv * gg[j] + bb[j];
  *(float4*)&Y[base] = y4;
  if (BF16OUT) {
#pragma unroll
    for (int j = 0; j < 4; ++j) Y2[base + j] = __float2bfloat16(yp[j]);
  }
}

extern "C" void kernel_launch(void* const* d_in, const int* in_sizes, int n_in,
                              void* d_out, int out_size, void* d_ws, size_t ws_size,
                              hipStream_t stream) {
  (void)in_sizes; (void)n_in; (void)out_size; (void)ws_size;
  const float* table = (const float*)d_in[0];
  const float* depm  = (const float*)d_in[1];
  const float* Wq = (const float*)d_in[2];   const float* bq = (const float*)d_in[3];
  const float* Wk = (const float*)d_in[4];   const float* bk = (const float*)d_in[5];
  const float* Wv = (const float*)d_in[6];   const float* bv = (const float*)d_in[7];
  const float* Wo = (const float*)d_in[8];   const float* bo = (const float*)d_in[9];
  const float* Wdep = (const float*)d_in[10]; const float* bdep = (const float*)d_in[11];
  const float* g1 = (const float*)d_in[12];  const float* be1 = (const float*)d_in[13];
  const float* W1 = (const float*)d_in[14];  const float* b1 = (const float*)d_in[15];
  const float* W2 = (const float*)d_in[16];  const float* b2 = (const float*)d_in[17];
  const float* g2 = (const float*)d_in[18];  const float* be2 = (const float*)d_in[19];

  // ws layout (bytes)
  char* ws = (char*)d_ws;
  size_t off = 0;
  __bf16* qkvb  = (__bf16*)(ws + off); off += (size_t)M_ROWS * 768 * 2;   // 56623104
  __bf16* ctxb  = (__bf16*)(ws + off); off += (size_t)M_ROWS * 256 * 2;   // 18874368
  float*  tmp   = (float*) (ws + off); off += (size_t)M_ROWS * 256 * 4;   // 37748736
  float*  outb  = (float*) (ws + off); off += (size_t)M_ROWS * 256 * 4;   // 37748736
  __bf16* outbb = (__bf16*)(ws + off); off += (size_t)M_ROWS * 256 * 2;   // 18874368
  __bf16* hidb  = (__bf16*)(ws + off); off += (size_t)M_ROWS * 1024 * 2;  // 75497472
  __bf16* tabb  = (__bf16*)(ws + off); off += (size_t)M_ROWS * 256 * 2;   // 18874368
  __bf16* Wqkv_t = (__bf16*)(ws + off); off += 768 * 256 * 2;
  __bf16* Wo_t   = (__bf16*)(ws + off); off += 256 * 256 * 2;
  __bf16* W1_t   = (__bf16*)(ws + off); off += 1024 * 256 * 2;
  __bf16* W2_t   = (__bf16*)(ws + off); off += 256 * 1024 * 2;
  float*  bqkv   = (float*)(ws + off);

  // 1. table -> bf16
  cvt_bf16_kernel<<<9216, 256, 0, stream>>>(table, tabb, M_ROWS * 256 / 4);
  // 2. pack weights (bf16, transposed) + bqkv
  pack_w_kernel<<<3072, 256, 0, stream>>>(Wq, Wk, Wv, Wo, W1, W2, bq, bk, bv,
                                          Wqkv_t, Wo_t, W1_t, W2_t, bqkv);
  // 3. qkv = table @ Wqkv + bqkv -> bf16 [M,768]
  gemm_mfma_kernel<0, true><<<dim3(6, 288), 256, 0, stream>>>(tabb, Wqkv_t, bqkv, nullptr, qkvb, 768, 256);
  // 4. attention -> ctx bf16 [M,256]
  attn_kernel<<<3072, 256, 0, stream>>>(qkvb, depm, Wdep, bdep, (__hip_bfloat16*)ctxb);
  // 5. tmp = ctx @ Wo + bo + table (fp32)
  gemm_mfma_kernel<2, false><<<dim3(2, 288), 256, 0, stream>>>(ctxb, Wo_t, bo, table, tmp, 256, 256);
  // 6. LN1 -> outb fp32 + outbb bf16
  ln_kernel<true><<<9216, 256, 0, stream>>>(tmp, g1, be1, outb, (__hip_bfloat16*)outbb);
  // 7. hidden = relu(outb @ W1 + b1) -> bf16 [M,1024]
  gemm_mfma_kernel<1, true><<<dim3(8, 288), 256, 0, stream>>>(outbb, W1_t, b1, nullptr, hidb, 1024, 256);
  // 8. tmp = hidden @ W2 + b2 + outb (fp32)
  gemm_mfma_kernel<2, false><<<dim3(2, 288), 256, 0, stream>>>(hidb, W2_t, b2, outb, tmp, 256, 1024);
  // 9. LN2 -> d_out fp32
  ln_kernel<false><<<9216, 256, 0, stream>>>(tmp, g2, be2, (float*)d_out, nullptr);
}

// Round 3
// 254.027 us; speedup vs baseline: 4.1716x; 1.7074x over previous
//
#include <hip/hip_runtime.h>
#include <hip/hip_bf16.h>
#include <math.h>

// Problem constants: B=4, L=96, D=256, H=8, hd=32, FF=1024. M = B*L*L = 36864.
#define M_ROWS 36864

typedef __bf16 bf16x8 __attribute__((ext_vector_type(8)));
typedef float f32x4 __attribute__((ext_vector_type(4)));

__device__ __forceinline__ void gload16(const void* g, void* l) {
  __builtin_amdgcn_global_load_lds((const __attribute__((address_space(1))) void*)g,
                                   (__attribute__((address_space(3))) void*)l, 16, 0, 0);
}

// ---------------- convert table fp32 -> bf16 ----------------
__global__ __launch_bounds__(256) void cvt_bf16_kernel(const float* __restrict__ X,
                                                       __bf16* __restrict__ Y, int n4) {
  int i = blockIdx.x * 256 + threadIdx.x;
  if (i >= n4) return;
  float4 x = *(const float4*)&X[(size_t)i * 4];
  __bf16* y = Y + (size_t)i * 4;
  y[0] = (__bf16)x.x; y[1] = (__bf16)x.y; y[2] = (__bf16)x.z; y[3] = (__bf16)x.w;
}

// ---------------- pack + transpose weights to bf16 B^T [N,K] ----------------
__global__ __launch_bounds__(256) void pack_w_kernel(
    const float* __restrict__ Wq, const float* __restrict__ Wk, const float* __restrict__ Wv,
    const float* __restrict__ Wo, const float* __restrict__ W1, const float* __restrict__ W2,
    const float* __restrict__ bq, const float* __restrict__ bk, const float* __restrict__ bv,
    __bf16* __restrict__ Wqkv_t, __bf16* __restrict__ Wo_t,
    __bf16* __restrict__ W1_t, __bf16* __restrict__ W2_t, float* __restrict__ bqkv) {
  int idx = blockIdx.x * 256 + threadIdx.x;
  const int S1 = 768 * 256, S2 = 256 * 256, S3 = 1024 * 256;
  if (idx < S1) {
    int n = idx / 256, k = idx % 256;
    int sel = n >> 8, nn = n & 255;
    const float* W = (sel == 0) ? Wq : (sel == 1) ? Wk : Wv;
    Wqkv_t[idx] = (__bf16)W[k * 256 + nn];
  } else if (idx < S1 + S2) {
    int j = idx - S1; int n = j / 256, k = j % 256;
    Wo_t[j] = (__bf16)Wo[k * 256 + n];
  } else if (idx < S1 + S2 + S3) {
    int j = idx - S1 - S2; int n = j / 256, k = j % 256;
    W1_t[j] = (__bf16)W1[k * 1024 + n];
  } else {
    int j = idx - S1 - S2 - S3; int n = j / 1024, k = j % 1024;
    W2_t[j] = (__bf16)W2[k * 256 + n];
  }
  if (idx < 768) {
    int sel = idx >> 8, jj = idx & 255;
    const float* bsrc = (sel == 0) ? bq : (sel == 1) ? bk : bv;
    bqkv[idx] = bsrc[jj];
  }
}

// ---------------- bf16 MFMA GEMM (m97 structure) ----------------
template <int EPI, bool OBF>
__global__ __launch_bounds__(256) void gemm_mfma_kernel(
    const __bf16* __restrict__ A, const __bf16* __restrict__ Bt,
    const float* __restrict__ bias, const float* __restrict__ resid,
    void* __restrict__ Cout, int N, int K) {
  __shared__ __bf16 As[128 * 64];
  __shared__ __bf16 Bs[128 * 64];
  const int tid = threadIdx.x;
  const int lane = tid & 63, wv = tid >> 6;
  const int wm = wv >> 1, wn = wv & 1;
  const int n0 = blockIdx.x * 128;
  const int m0 = blockIdx.y * 128;
  const int lrow = lane >> 3;
  const int lcol = (lane & 7) * 8;
  const int fr = lane & 15;
  const int fk = (lane >> 4) * 8;

  f32x4 acc[4][4] = {};

  for (int kb = 0; kb < K; kb += 64) {
    __syncthreads();
#pragma unroll
    for (int i = 0; i < 4; ++i) {
      const int row = i * 32 + wv * 8 + lrow;
      gload16(A + (size_t)(m0 + row) * K + kb + lcol, &As[i * 2048 + wv * 512]);
      gload16(Bt + (size_t)(n0 + row) * K + kb + lcol, &Bs[i * 2048 + wv * 512]);
    }
    __syncthreads();
#pragma unroll
    for (int s = 0; s < 2; ++s) {
      bf16x8 av[4], bv[4];
#pragma unroll
      for (int mi = 0; mi < 4; ++mi)
        av[mi] = *reinterpret_cast<const bf16x8*>(&As[(wm * 64 + mi * 16 + fr) * 64 + s * 32 + fk]);
#pragma unroll
      for (int ni = 0; ni < 4; ++ni)
        bv[ni] = *reinterpret_cast<const bf16x8*>(&Bs[(wn * 64 + ni * 16 + fr) * 64 + s * 32 + fk]);
#pragma unroll
      for (int mi = 0; mi < 4; ++mi)
#pragma unroll
        for (int ni = 0; ni < 4; ++ni)
          acc[mi][ni] = __builtin_amdgcn_mfma_f32_16x16x32_bf16(av[mi], bv[ni], acc[mi][ni], 0, 0, 0);
    }
  }

  const int crow = m0 + wm * 64 + (lane >> 4) * 4;
  const int ccol = n0 + wn * 64 + (lane & 15);
  __hip_bfloat16* outb = (__hip_bfloat16*)Cout;
  float* outf = (float*)Cout;
#pragma unroll
  for (int mi = 0; mi < 4; ++mi) {
#pragma unroll
    for (int ni = 0; ni < 4; ++ni) {
      const int col = ccol + ni * 16;
      const float bb = bias[col];
#pragma unroll
      for (int r = 0; r < 4; ++r) {
        const int row = crow + mi * 16 + r;
        float v = acc[mi][ni][r] + bb;
        if (EPI == 1) v = fmaxf(v, 0.f);
        if (EPI == 2) v += resid[(size_t)row * N + col];
        if (OBF) outb[(size_t)row * N + col] = __float2bfloat16(v);
        else     outf[(size_t)row * N + col] = v;
      }
    }
  }
}

// ---------------- MFMA attention: one block per (b,h,x), 6 waves ----------------
// Each wave owns 16 q-rows. S[16,96] = 6 mfma (K=32); softmax in-register;
// P (unnormalized) -> wave-private LDS; PV = 6 mfma; scale by 1/rowsum at write.
__global__ __launch_bounds__(384) void attn_mfma_kernel(
    const __bf16* __restrict__ qkv, const float* __restrict__ depm,
    const float* __restrict__ Wdep, const float* __restrict__ bdep,
    __hip_bfloat16* __restrict__ ctx) {
  __shared__ __bf16 Qs[96][40];     // pad->40: 2-way bank alias (free)
  __shared__ __bf16 Ks[96][40];
  __shared__ __bf16 Vt[32][104];    // V transposed at stage time
  __shared__ __bf16 Ps[6][16][104]; // per-wave P tile
  const int bid = blockIdx.x;
  const int x = bid % 96;
  const int h = (bid / 96) % 8;
  const int b = bid / (96 * 8);
  const int tid = threadIdx.x;
  const size_t slab = (size_t)(b * 96 + x) * 96;
  const size_t base = slab * 768 + h * 32;
  // stage 96 rows x {q,k,v} x 32 cols = 1152 16B segments, 3 per thread
#pragma unroll
  for (int t = 0; t < 3; ++t) {
    const int idx = tid + t * 384;
    const int r = idx / 12, rem = idx % 12, mat = rem >> 2, seg = rem & 3;
    const int d0 = seg * 8;
    bf16x8 v8 = *(const bf16x8*)&qkv[base + (size_t)r * 768 + mat * 256 + d0];
    if (mat == 0)      *(bf16x8*)&Qs[r][d0] = v8;
    else if (mat == 1) *(bf16x8*)&Ks[r][d0] = v8;
    else {
#pragma unroll
      for (int e = 0; e < 8; ++e) Vt[d0 + e][r] = v8[e];
    }
  }
  __syncthreads();
  const int wave = tid >> 6, lane = tid & 63;
  const int fr = lane & 15, g = lane >> 4;
  const int q0 = wave * 16;
  const float wd = Wdep[h], bd = bdep[h];
  float depb[6];
#pragma unroll
  for (int f = 0; f < 6; ++f) depb[f] = depm[slab + fr + 16 * f] * wd + bd;
  // --- QK^T: S[16,96], A=Q rows, B^T=K rows ---
  const bf16x8 av = *(const bf16x8*)&Qs[q0 + fr][g * 8];
  f32x4 sacc[6];
#pragma unroll
  for (int f = 0; f < 6; ++f) {
    const bf16x8 bv = *(const bf16x8*)&Ks[f * 16 + fr][g * 8];
    sacc[f] = __builtin_amdgcn_mfma_f32_16x16x32_bf16(av, bv, (f32x4){0.f, 0.f, 0.f, 0.f}, 0, 0, 0);
  }
  // --- softmax over 96 cols; C/D layout: col=fr+16f, row=4g+r ---
  const float scale = 0.17677669529663687f;  // 1/sqrt(32)
  float ev[6][4];
  float inv[4];
#pragma unroll
  for (int r = 0; r < 4; ++r) {
    float m = -1e30f;
#pragma unroll
    for (int f = 0; f < 6; ++f) {
      ev[f][r] = sacc[f][r] * scale + depb[f];
      m = fmaxf(m, ev[f][r]);
    }
#pragma unroll
    for (int o = 8; o > 0; o >>= 1) m = fmaxf(m, __shfl_xor(m, o));  // 16-lane group
    float sum = 0.f;
#pragma unroll
    for (int f = 0; f < 6; ++f) { ev[f][r] = __expf(ev[f][r] - m); sum += ev[f][r]; }
#pragma unroll
    for (int o = 8; o > 0; o >>= 1) sum += __shfl_xor(sum, o);
    inv[r] = 1.0f / sum;
  }
  // --- P (unnormalized) -> wave-private LDS in A-fragment layout ---
#pragma unroll
  for (int f = 0; f < 6; ++f)
#pragma unroll
    for (int r = 0; r < 4; ++r)
      Ps[wave][g * 4 + r][fr + 16 * f] = (__bf16)ev[f][r];
  asm volatile("s_waitcnt lgkmcnt(0)" ::: "memory");  // wave-private: no barrier needed
  // --- PV: O[16,32] = P[16,96] @ V[96,32], B^T = Vt ---
  f32x4 o0 = {0.f, 0.f, 0.f, 0.f}, o1 = {0.f, 0.f, 0.f, 0.f};
#pragma unroll
  for (int s = 0; s < 3; ++s) {
    const bf16x8 pa  = *(const bf16x8*)&Ps[wave][fr][s * 32 + g * 8];
    const bf16x8 vb0 = *(const bf16x8*)&Vt[fr][s * 32 + g * 8];
    const bf16x8 vb1 = *(const bf16x8*)&Vt[16 + fr][s * 32 + g * 8];
    o0 = __builtin_amdgcn_mfma_f32_16x16x32_bf16(pa, vb0, o0, 0, 0, 0);
    o1 = __builtin_amdgcn_mfma_f32_16x16x32_bf16(pa, vb1, o1, 0, 0, 0);
  }
  // --- epilogue: normalize rows, write ctx ---
  const size_t orow = (slab + q0 + g * 4) * 256 + h * 32;
#pragma unroll
  for (int r = 0; r < 4; ++r) {
    ctx[orow + (size_t)r * 256 + fr]      = __float2bfloat16(o0[r] * inv[r]);
    ctx[orow + (size_t)r * 256 + 16 + fr] = __float2bfloat16(o1[r] * inv[r]);
  }
}

// ---------------- LayerNorm over last dim 256; wave per row ----------------
template <bool BF16OUT>
__global__ __launch_bounds__(256) void ln_kernel(const float* __restrict__ X,
                                                 const float* __restrict__ g,
                                                 const float* __restrict__ beta,
                                                 float* __restrict__ Y,
                                                 __hip_bfloat16* __restrict__ Y2) {
  const int row = blockIdx.x * 4 + (threadIdx.x >> 6);
  const int lane = threadIdx.x & 63;
  const size_t base = (size_t)row * 256 + lane * 4;
  float4 x4 = *(const float4*)&X[base];
  float xs[4] = {x4.x, x4.y, x4.z, x4.w};
  float s = xs[0] + xs[1] + xs[2] + xs[3];
#pragma unroll
  for (int o = 32; o > 0; o >>= 1) s += __shfl_xor(s, o);
  const float mean = s * (1.0f / 256.0f);
  float vsum = 0.f;
#pragma unroll
  for (int j = 0; j < 4; ++j) { float d = xs[j] - mean; vsum += d * d; }
#pragma unroll
  for (int o = 32; o > 0; o >>= 1) vsum += __shfl_xor(vsum, o);
  const float inv = rsqrtf(vsum * (1.0f / 256.0f) + 1e-5f);
  float4 g4 = *(const float4*)&g[lane * 4];
  float4 b4 = *(const float4*)&beta[lane * 4];
  float gg[4] = {g4.x, g4.y, g4.z, g4.w};
  float bb[4] = {b4.x, b4.y, b4.z, b4.w};
  float4 y4;
  float* yp = &y4.x;
#pragma unroll
  for (int j = 0; j < 4; ++j) yp[j] = (xs[j] - mean) * inv * gg[j] + bb[j];
  *(float4*)&Y[base] = y4;
  if (BF16OUT) {
#pragma unroll
    for (int j = 0; j < 4; ++j) Y2[base + j] = __float2bfloat16(yp[j]);
  }
}

extern "C" void kernel_launch(void* const* d_in, const int* in_sizes, int n_in,
                              void* d_out, int out_size, void* d_ws, size_t ws_size,
                              hipStream_t stream) {
  (void)in_sizes; (void)n_in; (void)out_size; (void)ws_size;
  const float* table = (const float*)d_in[0];
  const float* depm  = (const float*)d_in[1];
  const float* Wq = (const float*)d_in[2];   const float* bq = (const float*)d_in[3];
  const float* Wk = (const float*)d_in[4];   const float* bk = (const float*)d_in[5];
  const float* Wv = (const float*)d_in[6];   const float* bv = (const float*)d_in[7];
  const float* Wo = (const float*)d_in[8];   const float* bo = (const float*)d_in[9];
  const float* Wdep = (const float*)d_in[10]; const float* bdep = (const float*)d_in[11];
  const float* g1 = (const float*)d_in[12];  const float* be1 = (const float*)d_in[13];
  const float* W1 = (const float*)d_in[14];  const float* b1 = (const float*)d_in[15];
  const float* W2 = (const float*)d_in[16];  const float* b2 = (const float*)d_in[17];
  const float* g2 = (const float*)d_in[18];  const float* be2 = (const float*)d_in[19];

  char* ws = (char*)d_ws;
  size_t off = 0;
  __bf16* qkvb  = (__bf16*)(ws + off); off += (size_t)M_ROWS * 768 * 2;
  __bf16* ctxb  = (__bf16*)(ws + off); off += (size_t)M_ROWS * 256 * 2;
  float*  tmp   = (float*) (ws + off); off += (size_t)M_ROWS * 256 * 4;
  float*  outb  = (float*) (ws + off); off += (size_t)M_ROWS * 256 * 4;
  __bf16* outbb = (__bf16*)(ws + off); off += (size_t)M_ROWS * 256 * 2;
  __bf16* hidb  = (__bf16*)(ws + off); off += (size_t)M_ROWS * 1024 * 2;
  __bf16* tabb  = (__bf16*)(ws + off); off += (size_t)M_ROWS * 256 * 2;
  __bf16* Wqkv_t = (__bf16*)(ws + off); off += 768 * 256 * 2;
  __bf16* Wo_t   = (__bf16*)(ws + off); off += 256 * 256 * 2;
  __bf16* W1_t   = (__bf16*)(ws + off); off += 1024 * 256 * 2;
  __bf16* W2_t   = (__bf16*)(ws + off); off += 256 * 1024 * 2;
  float*  bqkv   = (float*)(ws + off);

  cvt_bf16_kernel<<<9216, 256, 0, stream>>>(table, tabb, M_ROWS * 256 / 4);
  pack_w_kernel<<<3072, 256, 0, stream>>>(Wq, Wk, Wv, Wo, W1, W2, bq, bk, bv,
                                          Wqkv_t, Wo_t, W1_t, W2_t, bqkv);
  // qkv = table @ Wqkv + bqkv -> bf16 [M,768]
  gemm_mfma_kernel<0, true><<<dim3(6, 288), 256, 0, stream>>>(tabb, Wqkv_t, bqkv, nullptr, qkvb, 768, 256);
  // attention -> ctx bf16 [M,256]
  attn_mfma_kernel<<<3072, 384, 0, stream>>>(qkvb, depm, Wdep, bdep, (__hip_bfloat16*)ctxb);
  // tmp = ctx @ Wo + bo + table (fp32)
  gemm_mfma_kernel<2, false><<<dim3(2, 288), 256, 0, stream>>>(ctxb, Wo_t, bo, table, tmp, 256, 256);
  // LN1 -> outb fp32 + outbb bf16
  ln_kernel<true><<<9216, 256, 0, stream>>>(tmp, g1, be1, outb, (__hip_bfloat16*)outbb);
  // hidden = relu(outb @ W1 + b1) -> bf16 [M,1024]
  gemm_mfma_kernel<1, true><<<dim3(8, 288), 256, 0, stream>>>(outbb, W1_t, b1, nullptr, hidb, 1024, 256);
  // tmp = hidden @ W2 + b2 + outb (fp32)
  gemm_mfma_kernel<2, false><<<dim3(2, 288), 256, 0, stream>>>(hidb, W2_t, b2, outb, tmp, 256, 1024);
  // LN2 -> d_out fp32
  ln_kernel<false><<<9216, 256, 0, stream>>>(tmp, g2, be2, (float*)d_out, nullptr);
}

// Round 4
// 237.715 us; speedup vs baseline: 4.4579x; 1.0686x over previous
//
#include <hip/hip_runtime.h>
#include <hip/hip_bf16.h>
#include <math.h>

// Problem constants: B=4, L=96, D=256, H=8, hd=32, FF=1024. M = B*L*L = 36864.
#define M_ROWS 36864

typedef __bf16 bf16x8 __attribute__((ext_vector_type(8)));
typedef float f32x4 __attribute__((ext_vector_type(4)));

__device__ __forceinline__ void gload16(const void* g, void* l) {
  __builtin_amdgcn_global_load_lds((const __attribute__((address_space(1))) void*)g,
                                   (__attribute__((address_space(3))) void*)l, 16, 0, 0);
}

// ---------------- convert table fp32 -> bf16 ----------------
__global__ __launch_bounds__(256) void cvt_bf16_kernel(const float* __restrict__ X,
                                                       __bf16* __restrict__ Y, int n4) {
  int i = blockIdx.x * 256 + threadIdx.x;
  if (i >= n4) return;
  float4 x = *(const float4*)&X[(size_t)i * 4];
  __bf16* y = Y + (size_t)i * 4;
  y[0] = (__bf16)x.x; y[1] = (__bf16)x.y; y[2] = (__bf16)x.z; y[3] = (__bf16)x.w;
}

// ---------------- pack + transpose weights to bf16 B^T [N,K] ----------------
__global__ __launch_bounds__(256) void pack_w_kernel(
    const float* __restrict__ Wq, const float* __restrict__ Wk, const float* __restrict__ Wv,
    const float* __restrict__ Wo, const float* __restrict__ W1, const float* __restrict__ W2,
    const float* __restrict__ bq, const float* __restrict__ bk, const float* __restrict__ bv,
    __bf16* __restrict__ Wqkv_t, __bf16* __restrict__ Wo_t,
    __bf16* __restrict__ W1_t, __bf16* __restrict__ W2_t, float* __restrict__ bqkv) {
  int idx = blockIdx.x * 256 + threadIdx.x;
  const int S1 = 768 * 256, S2 = 256 * 256, S3 = 1024 * 256;
  if (idx < S1) {
    int n = idx / 256, k = idx % 256;
    int sel = n >> 8, nn = n & 255;
    const float* W = (sel == 0) ? Wq : (sel == 1) ? Wk : Wv;
    Wqkv_t[idx] = (__bf16)W[k * 256 + nn];
  } else if (idx < S1 + S2) {
    int j = idx - S1; int n = j / 256, k = j % 256;
    Wo_t[j] = (__bf16)Wo[k * 256 + n];
  } else if (idx < S1 + S2 + S3) {
    int j = idx - S1 - S2; int n = j / 256, k = j % 256;
    W1_t[j] = (__bf16)W1[k * 1024 + n];
  } else {
    int j = idx - S1 - S2 - S3; int n = j / 1024, k = j % 1024;
    W2_t[j] = (__bf16)W2[k * 256 + n];
  }
  if (idx < 768) {
    int sel = idx >> 8, jj = idx & 255;
    const float* bsrc = (sel == 0) ? bq : (sel == 1) ? bk : bv;
    bqkv[idx] = bsrc[jj];
  }
}

// ---------------- bf16 MFMA GEMM (m97 structure), 128x128 tile ----------------
// EPI: 0 = bias, 1 = bias+relu. OBF: bf16 output.
template <int EPI, bool OBF>
__global__ __launch_bounds__(256) void gemm_mfma_kernel(
    const __bf16* __restrict__ A, const __bf16* __restrict__ Bt,
    const float* __restrict__ bias, void* __restrict__ Cout, int N, int K) {
  __shared__ __bf16 As[128 * 64];
  __shared__ __bf16 Bs[128 * 64];
  const int tid = threadIdx.x;
  const int lane = tid & 63, wv = tid >> 6;
  const int wm = wv >> 1, wn = wv & 1;
  const int n0 = blockIdx.x * 128;
  const int m0 = blockIdx.y * 128;
  const int lrow = lane >> 3;
  const int lcol = (lane & 7) * 8;
  const int fr = lane & 15;
  const int fk = (lane >> 4) * 8;

  f32x4 acc[4][4] = {};

  for (int kb = 0; kb < K; kb += 64) {
    __syncthreads();
#pragma unroll
    for (int i = 0; i < 4; ++i) {
      const int row = i * 32 + wv * 8 + lrow;
      gload16(A + (size_t)(m0 + row) * K + kb + lcol, &As[i * 2048 + wv * 512]);
      gload16(Bt + (size_t)(n0 + row) * K + kb + lcol, &Bs[i * 2048 + wv * 512]);
    }
    __syncthreads();
#pragma unroll
    for (int s = 0; s < 2; ++s) {
      bf16x8 av[4], bv[4];
#pragma unroll
      for (int mi = 0; mi < 4; ++mi)
        av[mi] = *reinterpret_cast<const bf16x8*>(&As[(wm * 64 + mi * 16 + fr) * 64 + s * 32 + fk]);
#pragma unroll
      for (int ni = 0; ni < 4; ++ni)
        bv[ni] = *reinterpret_cast<const bf16x8*>(&Bs[(wn * 64 + ni * 16 + fr) * 64 + s * 32 + fk]);
#pragma unroll
      for (int mi = 0; mi < 4; ++mi)
#pragma unroll
        for (int ni = 0; ni < 4; ++ni)
          acc[mi][ni] = __builtin_amdgcn_mfma_f32_16x16x32_bf16(av[mi], bv[ni], acc[mi][ni], 0, 0, 0);
    }
  }

  const int crow = m0 + wm * 64 + (lane >> 4) * 4;
  const int ccol = n0 + wn * 64 + (lane & 15);
  __hip_bfloat16* outb = (__hip_bfloat16*)Cout;
  float* outf = (float*)Cout;
#pragma unroll
  for (int mi = 0; mi < 4; ++mi) {
#pragma unroll
    for (int ni = 0; ni < 4; ++ni) {
      const int col = ccol + ni * 16;
      const float bb = bias[col];
#pragma unroll
      for (int r = 0; r < 4; ++r) {
        const int row = crow + mi * 16 + r;
        float v = acc[mi][ni][r] + bb;
        if (EPI == 1) v = fmaxf(v, 0.f);
        if (OBF) outb[(size_t)row * N + col] = __float2bfloat16(v);
        else     outf[(size_t)row * N + col] = v;
      }
    }
  }
}

// ---------------- GEMM (N=256) + bias + fp32 residual + LayerNorm epilogue ----
// BM=64, BN=256(=N), 4 waves; each wave owns cols wv*64..wv*64+63 of rows m0..m0+63.
// LN per row is block-local: shfl over 16-lane groups + tiny LDS cross-wave reduce.
// EMIT_BF16: also write bf16 copy (for feeding next GEMM).
template <bool EMIT_BF16>
__global__ __launch_bounds__(256) void gemm_ln_kernel(
    const __bf16* __restrict__ A, const __bf16* __restrict__ Bt,
    const float* __restrict__ bias, const float* __restrict__ resid,
    const float* __restrict__ gamma, const float* __restrict__ beta,
    float* __restrict__ Yf, __hip_bfloat16* __restrict__ Yb, int K) {
  __shared__ __bf16 As[64 * 64];
  __shared__ __bf16 Bs[256 * 64];
  __shared__ float red[2][4][64];  // {sum,sumsq}[wave][row]
  const int tid = threadIdx.x;
  const int lane = tid & 63, wv = tid >> 6;
  const int m0 = blockIdx.x * 64;
  const int fr = lane & 15, g = lane >> 4;
  const int lrow = lane >> 3, lcol = (lane & 7) * 8;

  f32x4 acc[4][4] = {};  // [mi][ni]

  for (int kb = 0; kb < K; kb += 64) {
    __syncthreads();
#pragma unroll
    for (int i = 0; i < 2; ++i) {  // A: 64 rows, 16 per wave
      const int row = wv * 16 + i * 8 + lrow;
      gload16(A + (size_t)(m0 + row) * K + kb + lcol, &As[(wv * 16 + i * 8) * 64]);
    }
#pragma unroll
    for (int i = 0; i < 8; ++i) {  // B^T: 256 rows, 64 per wave
      const int row = wv * 64 + i * 8 + lrow;
      gload16(Bt + (size_t)row * K + kb + lcol, &Bs[(wv * 64 + i * 8) * 64]);
    }
    __syncthreads();
#pragma unroll
    for (int s = 0; s < 2; ++s) {
      bf16x8 av[4], bv[4];
#pragma unroll
      for (int mi = 0; mi < 4; ++mi)
        av[mi] = *reinterpret_cast<const bf16x8*>(&As[(mi * 16 + fr) * 64 + s * 32 + g * 8]);
#pragma unroll
      for (int ni = 0; ni < 4; ++ni)
        bv[ni] = *reinterpret_cast<const bf16x8*>(&Bs[(wv * 64 + ni * 16 + fr) * 64 + s * 32 + g * 8]);
#pragma unroll
      for (int mi = 0; mi < 4; ++mi)
#pragma unroll
        for (int ni = 0; ni < 4; ++ni)
          acc[mi][ni] = __builtin_amdgcn_mfma_f32_16x16x32_bf16(av[mi], bv[ni], acc[mi][ni], 0, 0, 0);
    }
  }

  // ---- epilogue: v = acc + bias + resid; LN over 256 cols per row ----
  const int colb = wv * 64 + fr;  // + ni*16
  float bb[4], gg[4], be[4];
#pragma unroll
  for (int ni = 0; ni < 4; ++ni) {
    bb[ni] = bias[colb + ni * 16];
    gg[ni] = gamma[colb + ni * 16];
    be[ni] = beta[colb + ni * 16];
  }
#pragma unroll
  for (int mi = 0; mi < 4; ++mi) {
#pragma unroll
    for (int r = 0; r < 4; ++r) {
      const int lr = mi * 16 + g * 4 + r;
      const size_t grow = (size_t)(m0 + lr) * 256;
      float s = 0.f, q = 0.f;
#pragma unroll
      for (int ni = 0; ni < 4; ++ni) {
        float v = acc[mi][ni][r] + bb[ni] + resid[grow + colb + ni * 16];
        acc[mi][ni][r] = v;
        s += v; q += v * v;
      }
#pragma unroll
      for (int o = 8; o > 0; o >>= 1) { s += __shfl_xor(s, o); q += __shfl_xor(q, o); }
      if (fr == 0) { red[0][wv][lr] = s; red[1][wv][lr] = q; }
    }
  }
  __syncthreads();
#pragma unroll
  for (int mi = 0; mi < 4; ++mi) {
#pragma unroll
    for (int r = 0; r < 4; ++r) {
      const int lr = mi * 16 + g * 4 + r;
      const size_t grow = (size_t)(m0 + lr) * 256;
      const float s = red[0][0][lr] + red[0][1][lr] + red[0][2][lr] + red[0][3][lr];
      const float q = red[1][0][lr] + red[1][1][lr] + red[1][2][lr] + red[1][3][lr];
      const float mean = s * (1.0f / 256.0f);
      const float var = q * (1.0f / 256.0f) - mean * mean;
      const float inv = rsqrtf(var + 1e-5f);
#pragma unroll
      for (int ni = 0; ni < 4; ++ni) {
        const float y = (acc[mi][ni][r] - mean) * inv * gg[ni] + be[ni];
        Yf[grow + colb + ni * 16] = y;
        if (EMIT_BF16) Yb[grow + colb + ni * 16] = __float2bfloat16(y);
      }
    }
  }
}

// ---------------- MFMA attention: one block per (b,h,x), 6 waves ----------------
__global__ __launch_bounds__(384) void attn_mfma_kernel(
    const __bf16* __restrict__ qkv, const float* __restrict__ depm,
    const float* __restrict__ Wdep, const float* __restrict__ bdep,
    __hip_bfloat16* __restrict__ ctx) {
  __shared__ __bf16 Qs[96][40];
  __shared__ __bf16 Ks[96][40];
  __shared__ __bf16 Vt[32][104];
  __shared__ __bf16 Ps[6][16][104];
  const int bid = blockIdx.x;
  const int x = bid % 96;
  const int h = (bid / 96) % 8;
  const int b = bid / (96 * 8);
  const int tid = threadIdx.x;
  const size_t slab = (size_t)(b * 96 + x) * 96;
  const size_t base = slab * 768 + h * 32;
#pragma unroll
  for (int t = 0; t < 3; ++t) {
    const int idx = tid + t * 384;
    const int r = idx / 12, rem = idx % 12, mat = rem >> 2, seg = rem & 3;
    const int d0 = seg * 8;
    bf16x8 v8 = *(const bf16x8*)&qkv[base + (size_t)r * 768 + mat * 256 + d0];
    if (mat == 0)      *(bf16x8*)&Qs[r][d0] = v8;
    else if (mat == 1) *(bf16x8*)&Ks[r][d0] = v8;
    else {
#pragma unroll
      for (int e = 0; e < 8; ++e) Vt[d0 + e][r] = v8[e];
    }
  }
  __syncthreads();
  const int wave = tid >> 6, lane = tid & 63;
  const int fr = lane & 15, g = lane >> 4;
  const int q0 = wave * 16;
  const float wd = Wdep[h], bd = bdep[h];
  float depb[6];
#pragma unroll
  for (int f = 0; f < 6; ++f) depb[f] = depm[slab + fr + 16 * f] * wd + bd;
  const bf16x8 av = *(const bf16x8*)&Qs[q0 + fr][g * 8];
  f32x4 sacc[6];
#pragma unroll
  for (int f = 0; f < 6; ++f) {
    const bf16x8 bv = *(const bf16x8*)&Ks[f * 16 + fr][g * 8];
    sacc[f] = __builtin_amdgcn_mfma_f32_16x16x32_bf16(av, bv, (f32x4){0.f, 0.f, 0.f, 0.f}, 0, 0, 0);
  }
  const float scale = 0.17677669529663687f;
  float ev[6][4];
  float inv[4];
#pragma unroll
  for (int r = 0; r < 4; ++r) {
    float m = -1e30f;
#pragma unroll
    for (int f = 0; f < 6; ++f) {
      ev[f][r] = sacc[f][r] * scale + depb[f];
      m = fmaxf(m, ev[f][r]);
    }
#pragma unroll
    for (int o = 8; o > 0; o >>= 1) m = fmaxf(m, __shfl_xor(m, o));
    float sum = 0.f;
#pragma unroll
    for (int f = 0; f < 6; ++f) { ev[f][r] = __expf(ev[f][r] - m); sum += ev[f][r]; }
#pragma unroll
    for (int o = 8; o > 0; o >>= 1) sum += __shfl_xor(sum, o);
    inv[r] = 1.0f / sum;
  }
#pragma unroll
  for (int f = 0; f < 6; ++f)
#pragma unroll
    for (int r = 0; r < 4; ++r)
      Ps[wave][g * 4 + r][fr + 16 * f] = (__bf16)ev[f][r];
  asm volatile("s_waitcnt lgkmcnt(0)" ::: "memory");
  f32x4 o0 = {0.f, 0.f, 0.f, 0.f}, o1 = {0.f, 0.f, 0.f, 0.f};
#pragma unroll
  for (int s = 0; s < 3; ++s) {
    const bf16x8 pa  = *(const bf16x8*)&Ps[wave][fr][s * 32 + g * 8];
    const bf16x8 vb0 = *(const bf16x8*)&Vt[fr][s * 32 + g * 8];
    const bf16x8 vb1 = *(const bf16x8*)&Vt[16 + fr][s * 32 + g * 8];
    o0 = __builtin_amdgcn_mfma_f32_16x16x32_bf16(pa, vb0, o0, 0, 0, 0);
    o1 = __builtin_amdgcn_mfma_f32_16x16x32_bf16(pa, vb1, o1, 0, 0, 0);
  }
  const size_t orow = (slab + q0 + g * 4) * 256 + h * 32;
#pragma unroll
  for (int r = 0; r < 4; ++r) {
    ctx[orow + (size_t)r * 256 + fr]      = __float2bfloat16(o0[r] * inv[r]);
    ctx[orow + (size_t)r * 256 + 16 + fr] = __float2bfloat16(o1[r] * inv[r]);
  }
}

extern "C" void kernel_launch(void* const* d_in, const int* in_sizes, int n_in,
                              void* d_out, int out_size, void* d_ws, size_t ws_size,
                              hipStream_t stream) {
  (void)in_sizes; (void)n_in; (void)out_size; (void)ws_size;
  const float* table = (const float*)d_in[0];
  const float* depm  = (const float*)d_in[1];
  const float* Wq = (const float*)d_in[2];   const float* bq = (const float*)d_in[3];
  const float* Wk = (const float*)d_in[4];   const float* bk = (const float*)d_in[5];
  const float* Wv = (const float*)d_in[6];   const float* bv = (const float*)d_in[7];
  const float* Wo = (const float*)d_in[8];   const float* bo = (const float*)d_in[9];
  const float* Wdep = (const float*)d_in[10]; const float* bdep = (const float*)d_in[11];
  const float* g1 = (const float*)d_in[12];  const float* be1 = (const float*)d_in[13];
  const float* W1 = (const float*)d_in[14];  const float* b1 = (const float*)d_in[15];
  const float* W2 = (const float*)d_in[16];  const float* b2 = (const float*)d_in[17];
  const float* g2 = (const float*)d_in[18];  const float* be2 = (const float*)d_in[19];

  char* ws = (char*)d_ws;
  size_t off = 0;
  __bf16* qkvb  = (__bf16*)(ws + off); off += (size_t)M_ROWS * 768 * 2;
  __bf16* ctxb  = (__bf16*)(ws + off); off += (size_t)M_ROWS * 256 * 2;
  float*  outb  = (float*) (ws + off); off += (size_t)M_ROWS * 256 * 4;
  __bf16* outbb = (__bf16*)(ws + off); off += (size_t)M_ROWS * 256 * 2;
  __bf16* hidb  = (__bf16*)(ws + off); off += (size_t)M_ROWS * 1024 * 2;
  __bf16* tabb  = (__bf16*)(ws + off); off += (size_t)M_ROWS * 256 * 2;
  __bf16* Wqkv_t = (__bf16*)(ws + off); off += 768 * 256 * 2;
  __bf16* Wo_t   = (__bf16*)(ws + off); off += 256 * 256 * 2;
  __bf16* W1_t   = (__bf16*)(ws + off); off += 1024 * 256 * 2;
  __bf16* W2_t   = (__bf16*)(ws + off); off += 256 * 1024 * 2;
  float*  bqkv   = (float*)(ws + off);

  cvt_bf16_kernel<<<9216, 256, 0, stream>>>(table, tabb, M_ROWS * 256 / 4);
  pack_w_kernel<<<3072, 256, 0, stream>>>(Wq, Wk, Wv, Wo, W1, W2, bq, bk, bv,
                                          Wqkv_t, Wo_t, W1_t, W2_t, bqkv);
  // qkv = table @ Wqkv + bqkv -> bf16 [M,768]
  gemm_mfma_kernel<0, true><<<dim3(6, 288), 256, 0, stream>>>(tabb, Wqkv_t, bqkv, qkvb, 768, 256);
  // attention -> ctx bf16 [M,256]
  attn_mfma_kernel<<<3072, 384, 0, stream>>>(qkvb, depm, Wdep, bdep, (__hip_bfloat16*)ctxb);
  // outb/outbb = LN1(ctx @ Wo + bo + table)  [fused]
  gemm_ln_kernel<true><<<576, 256, 0, stream>>>(ctxb, Wo_t, bo, table, g1, be1,
                                                outb, (__hip_bfloat16*)outbb, 256);
  // hidden = relu(outbb @ W1 + b1) -> bf16 [M,1024]
  gemm_mfma_kernel<1, true><<<dim3(8, 288), 256, 0, stream>>>(outbb, W1_t, b1, hidb, 1024, 256);
  // d_out = LN2(hidden @ W2 + b2 + outb)  [fused]
  gemm_ln_kernel<false><<<576, 256, 0, stream>>>(hidb, W2_t, b2, outb, g2, be2,
                                                 (float*)d_out, nullptr, 1024);
}

// Round 5
// 221.639 us; speedup vs baseline: 4.7812x; 1.0725x over previous
//
#include <hip/hip_runtime.h>
#include <hip/hip_bf16.h>
#include <math.h>

// Problem constants: B=4, L=96, D=256, H=8, hd=32, FF=1024. M = B*L*L = 36864.
#define M_ROWS 36864

typedef __bf16 bf16x8 __attribute__((ext_vector_type(8)));
typedef float f32x4 __attribute__((ext_vector_type(4)));

__device__ __forceinline__ void gload16(const void* g, void* l) {
  __builtin_amdgcn_global_load_lds((const __attribute__((address_space(1))) void*)g,
                                   (__attribute__((address_space(3))) void*)l, 16, 0, 0);
}

// ---------------- convert table fp32 -> bf16 (8 elems/thread) ----------------
__global__ __launch_bounds__(256) void cvt_bf16_kernel(const float* __restrict__ X,
                                                       __bf16* __restrict__ Y, int n8) {
  int i = blockIdx.x * 256 + threadIdx.x;
  if (i >= n8) return;
  const float4 a = ((const float4*)X)[(size_t)i * 2];
  const float4 b = ((const float4*)X)[(size_t)i * 2 + 1];
  bf16x8 o = {(__bf16)a.x, (__bf16)a.y, (__bf16)a.z, (__bf16)a.w,
              (__bf16)b.x, (__bf16)b.y, (__bf16)b.z, (__bf16)b.w};
  *(bf16x8*)&Y[(size_t)i * 8] = o;
}

// ---------------- pack + transpose weights to bf16 B^T [N,K] ----------------
__global__ __launch_bounds__(256) void pack_w_kernel(
    const float* __restrict__ Wq, const float* __restrict__ Wk, const float* __restrict__ Wv,
    const float* __restrict__ Wo, const float* __restrict__ W1, const float* __restrict__ W2,
    const float* __restrict__ bq, const float* __restrict__ bk, const float* __restrict__ bv,
    __bf16* __restrict__ Wqkv_t, __bf16* __restrict__ Wo_t,
    __bf16* __restrict__ W1_t, __bf16* __restrict__ W2_t, float* __restrict__ bqkv) {
  int idx = blockIdx.x * 256 + threadIdx.x;
  const int S1 = 768 * 256, S2 = 256 * 256, S3 = 1024 * 256;
  if (idx < S1) {
    int n = idx / 256, k = idx % 256;
    int sel = n >> 8, nn = n & 255;
    const float* W = (sel == 0) ? Wq : (sel == 1) ? Wk : Wv;
    Wqkv_t[idx] = (__bf16)W[k * 256 + nn];
  } else if (idx < S1 + S2) {
    int j = idx - S1; int n = j / 256, k = j % 256;
    Wo_t[j] = (__bf16)Wo[k * 256 + n];
  } else if (idx < S1 + S2 + S3) {
    int j = idx - S1 - S2; int n = j / 256, k = j % 256;
    W1_t[j] = (__bf16)W1[k * 1024 + n];
  } else {
    int j = idx - S1 - S2 - S3; int n = j / 1024, k = j % 1024;
    W2_t[j] = (__bf16)W2[k * 256 + n];
  }
  if (idx < 768) {
    int sel = idx >> 8, jj = idx & 255;
    const float* bsrc = (sel == 0) ? bq : (sel == 1) ? bk : bv;
    bqkv[idx] = bsrc[jj];
  }
}

// ---------------- bf16 MFMA GEMM: 128x128, 4 waves, 2-phase dbuf + swizzle ----
// EPI: 0 = bias, 1 = bias+relu. OBF: bf16 output.
// LDS bank fix: global source colseg pre-XORed with (row&7); reads XOR back.
template <int EPI, bool OBF>
__global__ __launch_bounds__(256) void gemm_mfma_kernel(
    const __bf16* __restrict__ A, const __bf16* __restrict__ Bt,
    const float* __restrict__ bias, void* __restrict__ Cout, int N, int K) {
  __shared__ __bf16 As[2][128 * 64];
  __shared__ __bf16 Bs[2][128 * 64];
  const int tid = threadIdx.x;
  const int lane = tid & 63, wv = tid >> 6;
  const int wm = wv >> 1, wn = wv & 1;
  // XCD-chunked block swizzle (nwg divisible by 8)
  const int gx = gridDim.x;
  const int nwg = gx * gridDim.y;
  int lin = blockIdx.y * gx + blockIdx.x;
  lin = (lin & 7) * (nwg >> 3) + (lin >> 3);
  const int n0 = (lin % gx) * 128;
  const int m0 = (lin / gx) * 128;
  const int lrow = lane >> 3;
  const int gcol = ((lane & 7) ^ (lrow & 7)) * 8;  // pre-swizzled source colseg
  const int fr = lane & 15, g = lane >> 4;

  f32x4 acc[4][4] = {};
  const int nkt = K >> 6;

#define STAGE_MM(buf, kb)                                                     \
  {                                                                           \
    _Pragma("unroll") for (int i = 0; i < 4; ++i) {                           \
      const int row = i * 32 + wv * 8 + lrow;                                 \
      gload16(A + (size_t)(m0 + row) * K + (kb) + gcol,                       \
              &As[buf][(i * 32 + wv * 8) * 64]);                              \
      gload16(Bt + (size_t)(n0 + row) * K + (kb) + gcol,                      \
              &Bs[buf][(i * 32 + wv * 8) * 64]);                              \
    }                                                                         \
  }

  STAGE_MM(0, 0)
  __syncthreads();  // implicit vmcnt(0) drain: buf0 ready
  int cur = 0;
  for (int kt = 0; kt < nkt; ++kt) {
    if (kt + 1 < nkt) STAGE_MM(cur ^ 1, (kt + 1) * 64)  // loads fly over compute
#pragma unroll
    for (int s = 0; s < 2; ++s) {
      bf16x8 av[4], bv[4];
      const int cs = (s * 4 + g) ^ (fr & 7);
#pragma unroll
      for (int mi = 0; mi < 4; ++mi)
        av[mi] = *reinterpret_cast<const bf16x8*>(&As[cur][(wm * 64 + mi * 16 + fr) * 64 + cs * 8]);
#pragma unroll
      for (int ni = 0; ni < 4; ++ni)
        bv[ni] = *reinterpret_cast<const bf16x8*>(&Bs[cur][(wn * 64 + ni * 16 + fr) * 64 + cs * 8]);
#pragma unroll
      for (int mi = 0; mi < 4; ++mi)
#pragma unroll
        for (int ni = 0; ni < 4; ++ni)
          acc[mi][ni] = __builtin_amdgcn_mfma_f32_16x16x32_bf16(av[mi], bv[ni], acc[mi][ni], 0, 0, 0);
    }
    __syncthreads();  // drains next-tile loads; protects buf reuse
    cur ^= 1;
  }
#undef STAGE_MM

  const int crow = m0 + wm * 64 + g * 4;
  const int ccol = n0 + wn * 64 + fr;
  __hip_bfloat16* outb = (__hip_bfloat16*)Cout;
  float* outf = (float*)Cout;
#pragma unroll
  for (int mi = 0; mi < 4; ++mi) {
#pragma unroll
    for (int ni = 0; ni < 4; ++ni) {
      const int col = ccol + ni * 16;
      const float bb = bias[col];
#pragma unroll
      for (int r = 0; r < 4; ++r) {
        const int row = crow + mi * 16 + r;
        float v = acc[mi][ni][r] + bb;
        if (EPI == 1) v = fmaxf(v, 0.f);
        if (OBF) outb[(size_t)row * N + col] = __float2bfloat16(v);
        else     outf[(size_t)row * N + col] = v;
      }
    }
  }
}

// ---------------- GEMM (N=256) + bias + fp32 resid + LayerNorm epilogue -------
// BM=64, BN=256, 4 waves; K-phases of 32 with 2-phase dbuf; swizzled LDS.
// Swizzle key = (row>>1)&3 so frag reads spread 16 lanes over 8 bank-quads.
template <bool EMIT_BF16>
__global__ __launch_bounds__(256) void gemm_ln_kernel(
    const __bf16* __restrict__ A, const __bf16* __restrict__ Bt,
    const float* __restrict__ bias, const float* __restrict__ resid,
    const float* __restrict__ gamma, const float* __restrict__ beta,
    float* __restrict__ Yf, __hip_bfloat16* __restrict__ Yb, int K) {
  __shared__ __bf16 As[2][64 * 32];
  __shared__ __bf16 Bs[2][256 * 32];
  __shared__ float red[2][4][64];
  const int tid = threadIdx.x;
  const int lane = tid & 63, wv = tid >> 6;
  const int nwg = gridDim.x;
  int lin = blockIdx.x;
  lin = (lin & 7) * (nwg >> 3) + (lin >> 3);
  const int m0 = lin * 64;
  const int fr = lane & 15, g = lane >> 4;
  const int arow = tid >> 2;                               // 0..63
  const int gcol = ((tid & 3) ^ ((tid >> 3) & 3)) * 8;     // pre-swizzled colseg

  f32x4 acc[4][4] = {};
  const int nph = K >> 5;

#define STAGE_LN(buf, kb)                                              \
  {                                                                    \
    gload16(A + (size_t)(m0 + arow) * K + (kb) + gcol,                 \
            &As[buf][wv * 512]);                                       \
    _Pragma("unroll") for (int i = 0; i < 4; ++i) {                    \
      gload16(Bt + (size_t)(i * 64 + arow) * K + (kb) + gcol,          \
              &Bs[buf][(i * 256 + wv * 64) * 8]);                      \
    }                                                                  \
  }

  STAGE_LN(0, 0)
  __syncthreads();
  int cur = 0;
  for (int p = 0; p < nph; ++p) {
    if (p + 1 < nph) STAGE_LN(cur ^ 1, (p + 1) * 32)
    const int cs = g ^ ((fr >> 1) & 3);
    bf16x8 av[4], bv[4];
#pragma unroll
    for (int mi = 0; mi < 4; ++mi)
      av[mi] = *reinterpret_cast<const bf16x8*>(&As[cur][(mi * 16 + fr) * 32 + cs * 8]);
#pragma unroll
    for (int ni = 0; ni < 4; ++ni)
      bv[ni] = *reinterpret_cast<const bf16x8*>(&Bs[cur][(wv * 64 + ni * 16 + fr) * 32 + cs * 8]);
#pragma unroll
    for (int mi = 0; mi < 4; ++mi)
#pragma unroll
      for (int ni = 0; ni < 4; ++ni)
        acc[mi][ni] = __builtin_amdgcn_mfma_f32_16x16x32_bf16(av[mi], bv[ni], acc[mi][ni], 0, 0, 0);
    __syncthreads();
    cur ^= 1;
  }
#undef STAGE_LN

  // ---- epilogue: v = acc + bias + resid; LN over 256 cols per row ----
  const int colb = wv * 64 + fr;  // + ni*16
  float bb[4], gg[4], be[4];
#pragma unroll
  for (int ni = 0; ni < 4; ++ni) {
    bb[ni] = bias[colb + ni * 16];
    gg[ni] = gamma[colb + ni * 16];
    be[ni] = beta[colb + ni * 16];
  }
#pragma unroll
  for (int mi = 0; mi < 4; ++mi) {
#pragma unroll
    for (int r = 0; r < 4; ++r) {
      const int lr = mi * 16 + g * 4 + r;
      const size_t grow = (size_t)(m0 + lr) * 256;
      float s = 0.f, q = 0.f;
#pragma unroll
      for (int ni = 0; ni < 4; ++ni) {
        float v = acc[mi][ni][r] + bb[ni] + resid[grow + colb + ni * 16];
        acc[mi][ni][r] = v;
        s += v; q += v * v;
      }
#pragma unroll
      for (int o = 8; o > 0; o >>= 1) { s += __shfl_xor(s, o); q += __shfl_xor(q, o); }
      if (fr == 0) { red[0][wv][lr] = s; red[1][wv][lr] = q; }
    }
  }
  __syncthreads();
#pragma unroll
  for (int mi = 0; mi < 4; ++mi) {
#pragma unroll
    for (int r = 0; r < 4; ++r) {
      const int lr = mi * 16 + g * 4 + r;
      const size_t grow = (size_t)(m0 + lr) * 256;
      const float s = red[0][0][lr] + red[0][1][lr] + red[0][2][lr] + red[0][3][lr];
      const float q = red[1][0][lr] + red[1][1][lr] + red[1][2][lr] + red[1][3][lr];
      const float mean = s * (1.0f / 256.0f);
      const float var = q * (1.0f / 256.0f) - mean * mean;
      const float inv = rsqrtf(var + 1e-5f);
#pragma unroll
      for (int ni = 0; ni < 4; ++ni) {
        const float y = (acc[mi][ni][r] - mean) * inv * gg[ni] + be[ni];
        Yf[grow + colb + ni * 16] = y;
        if (EMIT_BF16) Yb[grow + colb + ni * 16] = __float2bfloat16(y);
      }
    }
  }
}

// ---------------- MFMA attention: one block per (b,h,x), 6 waves ----------------
__global__ __launch_bounds__(384) void attn_mfma_kernel(
    const __bf16* __restrict__ qkv, const float* __restrict__ depm,
    const float* __restrict__ Wdep, const float* __restrict__ bdep,
    __hip_bfloat16* __restrict__ ctx) {
  __shared__ __bf16 Qs[96][40];
  __shared__ __bf16 Ks[96][40];
  __shared__ __bf16 Vt[32][104];
  __shared__ __bf16 Ps[6][16][104];
  // XCD swizzle: 8 heads of one (b,x) slab -> consecutive -> same XCD L2
  int lin = blockIdx.x;
  lin = (lin & 7) * 384 + (lin >> 3);
  const int h = lin & 7;
  const int sx = lin >> 3;          // 0..383
  const int x = sx % 96;
  const int b = sx / 96;
  const int tid = threadIdx.x;
  const size_t slab = (size_t)(b * 96 + x) * 96;
  const size_t base = slab * 768 + h * 32;
#pragma unroll
  for (int t = 0; t < 3; ++t) {
    const int idx = tid + t * 384;
    const int r = idx / 12, rem = idx % 12, mat = rem >> 2, seg = rem & 3;
    const int d0 = seg * 8;
    bf16x8 v8 = *(const bf16x8*)&qkv[base + (size_t)r * 768 + mat * 256 + d0];
    if (mat == 0)      *(bf16x8*)&Qs[r][d0] = v8;
    else if (mat == 1) *(bf16x8*)&Ks[r][d0] = v8;
    else {
#pragma unroll
      for (int e = 0; e < 8; ++e) Vt[d0 + e][r] = v8[e];
    }
  }
  __syncthreads();
  const int wave = tid >> 6, lane = tid & 63;
  const int fr = lane & 15, g = lane >> 4;
  const int q0 = wave * 16;
  const float wd = Wdep[h], bd = bdep[h];
  float depb[6];
#pragma unroll
  for (int f = 0; f < 6; ++f) depb[f] = depm[slab + fr + 16 * f] * wd + bd;
  const bf16x8 av = *(const bf16x8*)&Qs[q0 + fr][g * 8];
  f32x4 sacc[6];
#pragma unroll
  for (int f = 0; f < 6; ++f) {
    const bf16x8 bv = *(const bf16x8*)&Ks[f * 16 + fr][g * 8];
    sacc[f] = __builtin_amdgcn_mfma_f32_16x16x32_bf16(av, bv, (f32x4){0.f, 0.f, 0.f, 0.f}, 0, 0, 0);
  }
  const float scale = 0.17677669529663687f;
  float ev[6][4];
  float inv[4];
#pragma unroll
  for (int r = 0; r < 4; ++r) {
    float m = -1e30f;
#pragma unroll
    for (int f = 0; f < 6; ++f) {
      ev[f][r] = sacc[f][r] * scale + depb[f];
      m = fmaxf(m, ev[f][r]);
    }
#pragma unroll
    for (int o = 8; o > 0; o >>= 1) m = fmaxf(m, __shfl_xor(m, o));
    float sum = 0.f;
#pragma unroll
    for (int f = 0; f < 6; ++f) { ev[f][r] = __expf(ev[f][r] - m); sum += ev[f][r]; }
#pragma unroll
    for (int o = 8; o > 0; o >>= 1) sum += __shfl_xor(sum, o);
    inv[r] = 1.0f / sum;
  }
#pragma unroll
  for (int f = 0; f < 6; ++f)
#pragma unroll
    for (int r = 0; r < 4; ++r)
      Ps[wave][g * 4 + r][fr + 16 * f] = (__bf16)ev[f][r];
  asm volatile("s_waitcnt lgkmcnt(0)" ::: "memory");
  f32x4 o0 = {0.f, 0.f, 0.f, 0.f}, o1 = {0.f, 0.f, 0.f, 0.f};
#pragma unroll
  for (int s = 0; s < 3; ++s) {
    const bf16x8 pa  = *(const bf16x8*)&Ps[wave][fr][s * 32 + g * 8];
    const bf16x8 vb0 = *(const bf16x8*)&Vt[fr][s * 32 + g * 8];
    const bf16x8 vb1 = *(const bf16x8*)&Vt[16 + fr][s * 32 + g * 8];
    o0 = __builtin_amdgcn_mfma_f32_16x16x32_bf16(pa, vb0, o0, 0, 0, 0);
    o1 = __builtin_amdgcn_mfma_f32_16x16x32_bf16(pa, vb1, o1, 0, 0, 0);
  }
  const size_t orow = (slab + q0 + g * 4) * 256 + h * 32;
#pragma unroll
  for (int r = 0; r < 4; ++r) {
    ctx[orow + (size_t)r * 256 + fr]      = __float2bfloat16(o0[r] * inv[r]);
    ctx[orow + (size_t)r * 256 + 16 + fr] = __float2bfloat16(o1[r] * inv[r]);
  }
}

extern "C" void kernel_launch(void* const* d_in, const int* in_sizes, int n_in,
                              void* d_out, int out_size, void* d_ws, size_t ws_size,
                              hipStream_t stream) {
  (void)in_sizes; (void)n_in; (void)out_size; (void)ws_size;
  const float* table = (const float*)d_in[0];
  const float* depm  = (const float*)d_in[1];
  const float* Wq = (const float*)d_in[2];   const float* bq = (const float*)d_in[3];
  const float* Wk = (const float*)d_in[4];   const float* bk = (const float*)d_in[5];
  const float* Wv = (const float*)d_in[6];   const float* bv = (const float*)d_in[7];
  const float* Wo = (const float*)d_in[8];   const float* bo = (const float*)d_in[9];
  const float* Wdep = (const float*)d_in[10]; const float* bdep = (const float*)d_in[11];
  const float* g1 = (const float*)d_in[12];  const float* be1 = (const float*)d_in[13];
  const float* W1 = (const float*)d_in[14];  const float* b1 = (const float*)d_in[15];
  const float* W2 = (const float*)d_in[16];  const float* b2 = (const float*)d_in[17];
  const float* g2 = (const float*)d_in[18];  const float* be2 = (const float*)d_in[19];

  char* ws = (char*)d_ws;
  size_t off = 0;
  __bf16* qkvb  = (__bf16*)(ws + off); off += (size_t)M_ROWS * 768 * 2;
  __bf16* ctxb  = (__bf16*)(ws + off); off += (size_t)M_ROWS * 256 * 2;
  float*  outb  = (float*) (ws + off); off += (size_t)M_ROWS * 256 * 4;
  __bf16* outbb = (__bf16*)(ws + off); off += (size_t)M_ROWS * 256 * 2;
  __bf16* hidb  = (__bf16*)(ws + off); off += (size_t)M_ROWS * 1024 * 2;
  __bf16* tabb  = (__bf16*)(ws + off); off += (size_t)M_ROWS * 256 * 2;
  __bf16* Wqkv_t = (__bf16*)(ws + off); off += 768 * 256 * 2;
  __bf16* Wo_t   = (__bf16*)(ws + off); off += 256 * 256 * 2;
  __bf16* W1_t   = (__bf16*)(ws + off); off += 1024 * 256 * 2;
  __bf16* W2_t   = (__bf16*)(ws + off); off += 256 * 1024 * 2;
  float*  bqkv   = (float*)(ws + off);

  cvt_bf16_kernel<<<4608, 256, 0, stream>>>(table, tabb, M_ROWS * 256 / 8);
  pack_w_kernel<<<3072, 256, 0, stream>>>(Wq, Wk, Wv, Wo, W1, W2, bq, bk, bv,
                                          Wqkv_t, Wo_t, W1_t, W2_t, bqkv);
  // qkv = table @ Wqkv + bqkv -> bf16 [M,768]
  gemm_mfma_kernel<0, true><<<dim3(6, 288), 256, 0, stream>>>(tabb, Wqkv_t, bqkv, qkvb, 768, 256);
  // attention -> ctx bf16 [M,256]
  attn_mfma_kernel<<<3072, 384, 0, stream>>>(qkvb, depm, Wdep, bdep, (__hip_bfloat16*)ctxb);
  // outb/outbb = LN1(ctx @ Wo + bo + table)  [fused]
  gemm_ln_kernel<true><<<576, 256, 0, stream>>>(ctxb, Wo_t, bo, table, g1, be1,
                                                outb, (__hip_bfloat16*)outbb, 256);
  // hidden = relu(outbb @ W1 + b1) -> bf16 [M,1024]
  gemm_mfma_kernel<1, true><<<dim3(8, 288), 256, 0, stream>>>(outbb, W1_t, b1, hidb, 1024, 256);
  // d_out = LN2(hidden @ W2 + b2 + outb)  [fused]
  gemm_ln_kernel<false><<<576, 256, 0, stream>>>(hidb, W2_t, b2, outb, g2, be2,
                                                 (float*)d_out, nullptr, 1024);
}